// Round 4
// baseline (352.984 us; speedup 1.0000x reference)
//
#include <hip/hip_runtime.h>
#include <math.h>

#define NE 65536
#define NN 8192
#define CAP 128
#define NTMAX 20

typedef unsigned short u16;
typedef float f32x4 __attribute__((ext_vector_type(4)));
typedef __bf16 bf16x8 __attribute__((ext_vector_type(8)));
typedef unsigned short u16x8 __attribute__((ext_vector_type(8)));

// ---- ws layout (bytes); total 141,394,072 <= 141,394,176 (proven safe in R1) ----
#define WS_R1       0u           // 134,217,728: A[e][512] f32 (k_edge->k_msgs), then Dtmp[m][n][u] f32 (67MB)
#define WS_X        134217728u   // 4,194,304
#define WS_CH       138412032u   // 1,310,720  CH[lz=40][kc=16][u'=128][j=8] u16
#define WS_CL       139722752u   // 1,310,720
#define WS_COUNTS   141033472u   // 32,768 (counts; becomes cursor after k_scan)
#define WS_ZCNT     141066240u   // 64
#define WS_ROWSTART 141066304u   // 32,772
#define WS_ZRS      141099076u   // 44 (11 ints)
#define WS_ZCUR     141099120u   // 40
#define WS_ELIST    141099160u   // 262,144
#define WS_ZNODES   141361304u   // 32,768 -> end 141,394,072

__device__ __forceinline__ unsigned bf16_rne(float v) {
    unsigned u = __float_as_uint(v);
    return (u + 0x7FFFu + ((u >> 16) & 1u)) >> 16;
}

// ---------------- CSR build (edge by dst) + z-grouping of nodes ----------------
__global__ void k_count(const int* __restrict__ eidx, const float* __restrict__ na,
                        int* __restrict__ counts, int* __restrict__ zcnt) {
    int e = blockIdx.x * 256 + threadIdx.x;
    if (e < NE) atomicAdd(&counts[eidx[NE + e]], 1);
    if (e < NN) {
        const float* row = na + (size_t)e * 10;
        int z = 0;
        #pragma unroll
        for (int w = 1; w < 10; ++w) if (row[w] > 0.5f) z = w;
        atomicAdd(&zcnt[z], 1);
    }
}

__global__ __launch_bounds__(1024) void k_scan(int* __restrict__ counts,  // also becomes cursor
                                               int* __restrict__ row_start,
                                               const int* __restrict__ zcnt,
                                               int* __restrict__ zrs, int* __restrict__ zcur) {
    __shared__ int sd[1024];
    int t = threadIdx.x;
    int c[8];
    int s = 0;
    #pragma unroll
    for (int i = 0; i < 8; ++i) { c[i] = counts[t * 8 + i]; s += c[i]; }
    sd[t] = s;
    __syncthreads();
    for (int off = 1; off < 1024; off <<= 1) {
        int v = (t >= off) ? sd[t - off] : 0;
        __syncthreads();
        sd[t] += v;
        __syncthreads();
    }
    int run = (t == 0) ? 0 : sd[t - 1];
    #pragma unroll
    for (int i = 0; i < 8; ++i) {
        row_start[t * 8 + i] = run;
        counts[t * 8 + i] = run;   // cursor
        run += c[i];
    }
    if (t == 1023) row_start[8192] = run;
    if (t == 0) {
        int zr = 0;
        for (int i = 0; i < 10; ++i) { zrs[i] = zr; zcur[i] = zr; zr += zcnt[i]; }
        zrs[10] = zr;
    }
}

__global__ void k_scatter(const int* __restrict__ eidx, const float* __restrict__ na,
                          int* __restrict__ cursor, int* __restrict__ elist,
                          int* __restrict__ zcur, int* __restrict__ znodes) {
    int e = blockIdx.x * 256 + threadIdx.x;
    if (e < NE) {
        int p = atomicAdd(&cursor[eidx[NE + e]], 1);
        elist[p] = e;
    }
    if (e < NN) {
        const float* row = na + (size_t)e * 10;
        int z = 0;
        #pragma unroll
        for (int w = 1; w < 10; ++w) if (row[w] > 0.5f) z = w;
        int p = atomicAdd(&zcur[z], 1);
        znodes[p] = e;
    }
}

// ---------------- x = node_feats @ W_up / sqrt(128) ----------------
__global__ __launch_bounds__(256) void k_x(const float* __restrict__ nf,
                                           const float* __restrict__ Wup,
                                           float* __restrict__ x) {
    __shared__ float nf_s[16][128];
    int n0 = blockIdx.x * 16;
    int t = threadIdx.x;
    for (int i = t; i < 16 * 128; i += 256) nf_s[i >> 7][i & 127] = nf[n0 * 128 + i];
    __syncthreads();
    int mc = t & 127, half = t >> 7;
    float acc[8];
    #pragma unroll
    for (int j = 0; j < 8; ++j) acc[j] = 0.f;
    for (int k = 0; k < 128; ++k) {
        float w = Wup[k * 128 + mc];
        #pragma unroll
        for (int j = 0; j < 8; ++j) acc[j] += nf_s[half * 8 + j][k] * w;
    }
    const float rs = 0.08838834764831845f;  // 1/sqrt(128)
    #pragma unroll
    for (int j = 0; j < 8; ++j) x[(n0 + half * 8 + j) * 128 + mc] = acc[j] * rs;
}

// ---------------- C precompute -> split-bf16 in MFMA A-frag layout ----------------
// CH/CL[lz][kc][u'][j] = bf16 split of scale * sum_v W_lin[l][u=kc*8+j][v] * W_skip[l][v][z][u']
__global__ __launch_bounds__(256) void k_C(const float* __restrict__ Wlin,
                                           const float* __restrict__ Wskip,
                                           u16* __restrict__ CH, u16* __restrict__ CL) {
    __shared__ float wl_s[16][128];
    int b = blockIdx.x;
    int lz = b >> 3, ut = b & 7;
    int l = lz / 10, z = lz % 10;
    int t = threadIdx.x;
    for (int i = t; i < 16 * 128; i += 256) {
        int u = i >> 7, v = i & 127;
        wl_s[u][v] = Wlin[(l * 128 + ut * 16 + u) * 128 + v];
    }
    __syncthreads();
    int u2 = t & 127, uh = t >> 7;
    float acc[8];
    #pragma unroll
    for (int r = 0; r < 8; ++r) acc[r] = 0.f;
    const float* Wsk = Wskip + ((size_t)l * 128 * 10 + z) * 128 + u2;  // stride over v: 1280
    for (int v = 0; v < 128; v += 4) {
        float s0 = Wsk[(size_t)(v + 0) * 1280];
        float s1 = Wsk[(size_t)(v + 1) * 1280];
        float s2 = Wsk[(size_t)(v + 2) * 1280];
        float s3 = Wsk[(size_t)(v + 3) * 1280];
        #pragma unroll
        for (int r = 0; r < 8; ++r) {
            int u = uh * 8 + r;
            acc[r] += wl_s[u][v] * s0 + wl_s[u][v + 1] * s1
                    + wl_s[u][v + 2] * s2 + wl_s[u][v + 3] * s3;
        }
    }
    const float scale = 3.0881618e-04f;  // (1/sqrt(128)/8) * (1/sqrt(1280))
    int kc = ut * 2 + uh;
    u16x8 vh, vl;
    #pragma unroll
    for (int r = 0; r < 8; ++r) {
        float v = acc[r] * scale;
        unsigned h = bf16_rne(v);
        float fh = __uint_as_float(h << 16);
        unsigned lo = bf16_rne(v - fh);
        vh[r] = (u16)h;
        vl[r] = (u16)lo;
    }
    size_t off = ((size_t)(lz * 16 + kc) * 128 + u2) * 8;
    *(u16x8*)(CH + off) = vh;
    *(u16x8*)(CL + off) = vl;
}

// ---------------- edge MLP + W4 GEMM + x-gather epilogue -> A[e][512] ----------------
__global__ __launch_bounds__(256) void k_edge(const float* __restrict__ ef,
                                              const int* __restrict__ eidx,
                                              const float* __restrict__ W1, const float* __restrict__ b1,
                                              const float* __restrict__ W2, const float* __restrict__ b2,
                                              const float* __restrict__ W3, const float* __restrict__ b3,
                                              const float* __restrict__ W4, const float* __restrict__ b4,
                                              const float* __restrict__ x,
                                              float* __restrict__ A) {
    __shared__ float ef_s[32][8];
    __shared__ float ha[32][65];
    __shared__ float hb[32][65];
    int t = threadIdx.x;
    int e0 = blockIdx.x * 32;
    ef_s[t >> 3][t & 7] = ef[e0 * 8 + t];
    __syncthreads();
    int lane = t & 63, wv = t >> 6;
    #pragma unroll
    for (int j = 0; j < 8; ++j) {
        int e = wv + 4 * j;
        float s = b1[lane];
        #pragma unroll
        for (int i = 0; i < 8; ++i) s += ef_s[e][i] * W1[i * 64 + lane];
        ha[e][lane] = s / (1.f + expf(-s));
    }
    __syncthreads();
    #pragma unroll
    for (int j = 0; j < 8; ++j) {
        int e = wv + 4 * j;
        float s = b2[lane];
        #pragma unroll 8
        for (int i = 0; i < 64; ++i) s += ha[e][i] * W2[i * 64 + lane];
        hb[e][lane] = s / (1.f + expf(-s));
    }
    __syncthreads();
    #pragma unroll
    for (int j = 0; j < 8; ++j) {
        int e = wv + 4 * j;
        float s = b3[lane];
        #pragma unroll 8
        for (int i = 0; i < 64; ++i) s += hb[e][i] * W3[i * 64 + lane];
        ha[e][lane] = s / (1.f + expf(-s));
    }
    __syncthreads();
    int cl = t & 63, rg = t >> 6;
    float acc[8][8];
    #pragma unroll
    for (int r = 0; r < 8; ++r)
        #pragma unroll
        for (int j = 0; j < 8; ++j) acc[r][j] = 0.f;
    for (int k = 0; k < 64; ++k) {
        float w4v[8];
        #pragma unroll
        for (int j = 0; j < 8; ++j) w4v[j] = W4[k * 512 + cl + 64 * j];
        #pragma unroll
        for (int r = 0; r < 8; ++r) {
            float hv = ha[rg * 8 + r][k];
            #pragma unroll
            for (int j = 0; j < 8; ++j) acc[r][j] += hv * w4v[j];
        }
    }
    float b4v[8];
    #pragma unroll
    for (int j = 0; j < 8; ++j) b4v[j] = b4[cl + 64 * j];
    #pragma unroll
    for (int r = 0; r < 8; ++r) {
        int e = e0 + rg * 8 + r;
        int src = eidx[e];
        float xv0 = x[src * 128 + cl];
        float xv1 = x[src * 128 + cl + 64];
        #pragma unroll
        for (int j = 0; j < 8; ++j) {
            float tpw = acc[r][j] + b4v[j];
            A[e * 512 + cl + 64 * j] = tpw * ((j & 1) ? xv1 : xv0);
        }
    }
}

// ---------------- per-node msg accumulation -> split-bf16 planes [m][n][u] ----------------
__global__ __launch_bounds__(256) void k_msgs(const float* __restrict__ A,
                                              const float* __restrict__ Y,
                                              const int* __restrict__ row_start,
                                              const int* __restrict__ elist,
                                              u16* __restrict__ MH, u16* __restrict__ ML) {
    __shared__ int el_s[CAP];
    int n = blockIdx.x;
    int t = threadIdx.x;
    int r0 = row_start[n], r1 = row_start[n + 1];
    int k = r1 - r0;
    for (int i = t; i < k && i < CAP; i += 256) el_s[i] = elist[r0 + i];
    __syncthreads();
    if (t == 0 && k <= CAP) {  // canonical order -> deterministic f32 sums
        for (int i = 1; i < k; ++i) {
            int key = el_s[i];
            int j = i - 1;
            while (j >= 0 && el_s[j] > key) { el_s[j + 1] = el_s[j]; --j; }
            el_s[j + 1] = key;
        }
    }
    __syncthreads();
    int mc = t & 127, hi = t >> 7;
    float acc[8];
    #pragma unroll
    for (int q = 0; q < 8; ++q) acc[q] = 0.f;
    for (int j = 0; j < k; ++j) {
        int e = (j < CAP) ? el_s[j] : elist[r0 + j];
        const float* Ae = A + (size_t)e * 512;
        const float* Ye = Y + e * 16 + hi * 8;
        float y[8];
        #pragma unroll
        for (int q = 0; q < 8; ++q) y[q] = Ye[q];
        if (hi == 0) {
            float a0 = Ae[mc], a1 = Ae[128 + mc], a2 = Ae[256 + mc];
            acc[0] += a0 * y[0];
            acc[1] += a1 * y[1]; acc[2] += a1 * y[2]; acc[3] += a1 * y[3];
            acc[4] += a2 * y[4]; acc[5] += a2 * y[5]; acc[6] += a2 * y[6]; acc[7] += a2 * y[7];
        } else {
            float a2 = Ae[256 + mc], a3 = Ae[384 + mc];
            acc[0] += a2 * y[0];
            #pragma unroll
            for (int q = 1; q < 8; ++q) acc[q] += a3 * y[q];
        }
    }
    #pragma unroll
    for (int q = 0; q < 8; ++q) {
        int m = hi * 8 + q;
        float v = acc[q];
        unsigned h = bf16_rne(v);
        float fh = __uint_as_float(h << 16);
        unsigned lo = bf16_rne(v - fh);
        size_t off = ((size_t)m * 8192 + n) * 128 + mc;
        MH[off] = (u16)h;
        ML[off] = (u16)lo;
    }
}

// ---------------- z-grouped split-bf16 MFMA contraction ----------------
// block = (z, plane, node-tile64): D[128 u'][64 cols] = C_l[z]^T x msgs_plane
__global__ __launch_bounds__(256) void k_contract(const u16* __restrict__ MH,
                                                  const u16* __restrict__ ML,
                                                  const u16* __restrict__ CH,
                                                  const u16* __restrict__ CL,
                                                  const int* __restrict__ zrs,
                                                  const int* __restrict__ znodes,
                                                  float* __restrict__ Dtmp) {
    int bx = blockIdx.x;
    int z = bx / (16 * NTMAX);
    int rem = bx % (16 * NTMAX);
    int plane = rem / NTMAX;
    int tile = rem % NTMAX;
    int l = (plane >= 9) ? 3 : (plane >= 4) ? 2 : (plane >= 1) ? 1 : 0;
    int base = zrs[z];
    int cz = zrs[z + 1] - base;
    int p0 = tile * 64;
    if (p0 >= cz) return;
    __shared__ int nid_s[64];
    int t = threadIdx.x;
    if (t < 64) nid_s[t] = (p0 + t < cz) ? znodes[base + p0 + t] : -1;
    __syncthreads();
    int w = t >> 6;           // wave -> M rows w*32..w*32+31
    int lane = t & 63;
    int colq = lane & 15;     // A row / B col / D col (lane&15)
    int krow = lane >> 4;
    int lz = l * 10 + z;
    f32x4 acc[2][4];
    #pragma unroll
    for (int i = 0; i < 2; ++i)
        #pragma unroll
        for (int j = 0; j < 4; ++j) acc[i][j] = (f32x4){0.f, 0.f, 0.f, 0.f};
    int nids[4];
    #pragma unroll
    for (int nt = 0; nt < 4; ++nt) {
        int v = nid_s[nt * 16 + colq];
        nids[nt] = (v < 0) ? 0 : v;
    }
    const u16* MHm = MH + (size_t)plane * (8192 * 128);
    const u16* MLm = ML + (size_t)plane * (8192 * 128);
    int u0 = w * 32 + colq;
    #pragma unroll
    for (int kt = 0; kt < 4; ++kt) {
        int kc = kt * 4 + krow;
        size_t abase = (size_t)(lz * 16 + kc) * 128;
        bf16x8 aH0 = *(const bf16x8*)(CH + (abase + u0) * 8);
        bf16x8 aL0 = *(const bf16x8*)(CL + (abase + u0) * 8);
        bf16x8 aH1 = *(const bf16x8*)(CH + (abase + u0 + 16) * 8);
        bf16x8 aL1 = *(const bf16x8*)(CL + (abase + u0 + 16) * 8);
        #pragma unroll
        for (int nt = 0; nt < 4; ++nt) {
            size_t boff = ((size_t)nids[nt] * 16 + kc) * 8;
            bf16x8 bH = *(const bf16x8*)(MHm + boff);
            bf16x8 bL = *(const bf16x8*)(MLm + boff);
            acc[0][nt] = __builtin_amdgcn_mfma_f32_16x16x32_bf16(aH0, bH, acc[0][nt], 0, 0, 0);
            acc[0][nt] = __builtin_amdgcn_mfma_f32_16x16x32_bf16(aH0, bL, acc[0][nt], 0, 0, 0);
            acc[0][nt] = __builtin_amdgcn_mfma_f32_16x16x32_bf16(aL0, bH, acc[0][nt], 0, 0, 0);
            acc[1][nt] = __builtin_amdgcn_mfma_f32_16x16x32_bf16(aH1, bH, acc[1][nt], 0, 0, 0);
            acc[1][nt] = __builtin_amdgcn_mfma_f32_16x16x32_bf16(aH1, bL, acc[1][nt], 0, 0, 0);
            acc[1][nt] = __builtin_amdgcn_mfma_f32_16x16x32_bf16(aL1, bH, acc[1][nt], 0, 0, 0);
        }
    }
    #pragma unroll
    for (int nt = 0; nt < 4; ++nt) {
        int nid = nid_s[nt * 16 + colq];
        if (nid < 0) continue;
        #pragma unroll
        for (int mt = 0; mt < 2; ++mt) {
            int up = w * 32 + mt * 16 + krow * 4;   // D row = (lane>>4)*4 + reg
            *(f32x4*)(Dtmp + ((size_t)plane * 8192 + nid) * 128 + up) = acc[mt][nt];
        }
    }
}

// ---------------- transpose-copy Dtmp[m][n][u] -> out[n][u][m] ----------------
__global__ __launch_bounds__(256) void k_copy(const float* __restrict__ Dtmp,
                                              float* __restrict__ out) {
    __shared__ float s[8 * 128 * 17];
    int n0 = blockIdx.x * 8;
    int t = threadIdx.x;
    for (int m = 0; m < 16; ++m) {
        #pragma unroll
        for (int it = 0; it < 4; ++it) {
            int i = it * 256 + t;  // i = nn*128 + u
            float v = Dtmp[(size_t)m * (8192 * 128) + (size_t)n0 * 128 + i];
            s[i * 17 + m] = v;
        }
    }
    __syncthreads();
    #pragma unroll
    for (int it = 0; it < 4; ++it) {
        int i = it * 256 + t;
        const float* sp = &s[i * 17];
        float4* dst = (float4*)(out + (size_t)n0 * 2048 + (size_t)i * 16);
        dst[0] = make_float4(sp[0], sp[1], sp[2], sp[3]);
        dst[1] = make_float4(sp[4], sp[5], sp[6], sp[7]);
        dst[2] = make_float4(sp[8], sp[9], sp[10], sp[11]);
        dst[3] = make_float4(sp[12], sp[13], sp[14], sp[15]);
    }
}

extern "C" void kernel_launch(void* const* d_in, const int* in_sizes, int n_in,
                              void* d_out, int out_size, void* d_ws, size_t ws_size,
                              hipStream_t stream) {
    const float* na   = (const float*)d_in[0];
    const float* nf   = (const float*)d_in[1];
    const float* ea   = (const float*)d_in[2];
    const float* ef   = (const float*)d_in[3];
    const int*   eidx = (const int*)d_in[4];
    const float* Wup  = (const float*)d_in[5];
    const float* W1   = (const float*)d_in[6];
    const float* b1   = (const float*)d_in[7];
    const float* W2   = (const float*)d_in[8];
    const float* b2   = (const float*)d_in[9];
    const float* W3   = (const float*)d_in[10];
    const float* b3   = (const float*)d_in[11];
    const float* W4   = (const float*)d_in[12];
    const float* b4   = (const float*)d_in[13];
    const float* Wlin = (const float*)d_in[14];
    const float* Wskip= (const float*)d_in[15];
    float* out = (float*)d_out;

    char* ws = (char*)d_ws;
    float* A        = (float*)(ws + WS_R1);
    float* Dtmp     = (float*)(ws + WS_R1);     // reuses A's region after k_msgs
    float* x        = (float*)(ws + WS_X);
    u16*   CH       = (u16*)(ws + WS_CH);
    u16*   CL       = (u16*)(ws + WS_CL);
    int*   counts   = (int*)(ws + WS_COUNTS);   // becomes cursor after k_scan
    int*   zcnt     = (int*)(ws + WS_ZCNT);
    int*   rowstart = (int*)(ws + WS_ROWSTART);
    int*   zrs      = (int*)(ws + WS_ZRS);
    int*   zcur     = (int*)(ws + WS_ZCUR);
    int*   elist    = (int*)(ws + WS_ELIST);
    int*   znodes   = (int*)(ws + WS_ZNODES);

    u16* MH = (u16*)d_out;                      // d_out doubles as msgs scratch (exactly 64 MB)
    u16* ML = MH + 16777216;

    hipMemsetAsync(counts, 0, 32768 + 64, stream);  // counts + zcnt
    k_count<<<NE / 256, 256, 0, stream>>>(eidx, na, counts, zcnt);
    k_scan<<<1, 1024, 0, stream>>>(counts, rowstart, zcnt, zrs, zcur);
    k_scatter<<<NE / 256, 256, 0, stream>>>(eidx, na, counts, elist, zcur, znodes);
    k_x<<<NN / 16, 256, 0, stream>>>(nf, Wup, x);
    k_C<<<320, 256, 0, stream>>>(Wlin, Wskip, CH, CL);
    k_edge<<<NE / 32, 256, 0, stream>>>(ef, eidx, W1, b1, W2, b2, W3, b3, W4, b4, x, A);
    k_msgs<<<NN, 256, 0, stream>>>(A, ea, rowstart, elist, MH, ML);
    k_contract<<<10 * 16 * NTMAX, 256, 0, stream>>>(MH, ML, CH, CL, zrs, znodes, Dtmp);
    k_copy<<<NN / 8, 256, 0, stream>>>(Dtmp, out);
}

// Round 5
// 345.856 us; speedup vs baseline: 1.0206x; 1.0206x over previous
//
#include <hip/hip_runtime.h>
#include <math.h>

#define NE 65536
#define NN 8192
#define CAP 128
#define NTMAX 20

typedef unsigned short u16;
typedef float f32x4 __attribute__((ext_vector_type(4)));
typedef __bf16 bf16x8 __attribute__((ext_vector_type(8)));
typedef unsigned short u16x8 __attribute__((ext_vector_type(8)));

// ---- ws layout (bytes); total 141,394,072 (proven safe R1/R2/R4) ----
#define WS_R1       0u           // 134,217,728: A[e][512] f32 (k_edge->k_msgs), then Dtmp[m][n][u] f32 (67MB)
#define WS_X        134217728u   // 4,194,304
#define WS_CH       138412032u   // 1,310,720  CH[lz=40][kc=16][u'=128][j=8] u16
#define WS_CL       139722752u   // 1,310,720
#define WS_COUNTS   141033472u   // 32,768 (counts; becomes cursor after k_scan)
#define WS_ZCNT     141066240u   // 64
#define WS_ROWSTART 141066304u   // 32,772
#define WS_ZRS      141099076u   // 44 (11 ints)
#define WS_ZCUR     141099120u   // 40
#define WS_ELIST    141099160u   // 262,144
#define WS_ZNODES   141361304u   // 32,768 -> end 141,394,072

// ---- d_out scratch layout for k_prep weights (overwritten later by k_msgs) ----
// f32: W1T[64][8] @0, W2T[64][64] @512, W3T[64][64] @4608 (float indices)
// u16: W4Th[512][64] @byte 34816, W4Tl @byte 100352  -> end 165,888 bytes << 64MB

__device__ __forceinline__ unsigned bf16_rne(float v) {
    unsigned u = __float_as_uint(v);
    return (u + 0x7FFFu + ((u >> 16) & 1u)) >> 16;
}

// ---------------- CSR build (edge by dst) + z-grouping of nodes ----------------
__global__ void k_count(const int* __restrict__ eidx, const float* __restrict__ na,
                        int* __restrict__ counts, int* __restrict__ zcnt) {
    int e = blockIdx.x * 256 + threadIdx.x;
    if (e < NE) atomicAdd(&counts[eidx[NE + e]], 1);
    if (e < NN) {
        const float* row = na + (size_t)e * 10;
        int z = 0;
        #pragma unroll
        for (int w = 1; w < 10; ++w) if (row[w] > 0.5f) z = w;
        atomicAdd(&zcnt[z], 1);
    }
}

__global__ __launch_bounds__(1024) void k_scan(int* __restrict__ counts,  // also becomes cursor
                                               int* __restrict__ row_start,
                                               const int* __restrict__ zcnt,
                                               int* __restrict__ zrs, int* __restrict__ zcur) {
    __shared__ int sd[1024];
    int t = threadIdx.x;
    int c[8];
    int s = 0;
    #pragma unroll
    for (int i = 0; i < 8; ++i) { c[i] = counts[t * 8 + i]; s += c[i]; }
    sd[t] = s;
    __syncthreads();
    for (int off = 1; off < 1024; off <<= 1) {
        int v = (t >= off) ? sd[t - off] : 0;
        __syncthreads();
        sd[t] += v;
        __syncthreads();
    }
    int run = (t == 0) ? 0 : sd[t - 1];
    #pragma unroll
    for (int i = 0; i < 8; ++i) {
        row_start[t * 8 + i] = run;
        counts[t * 8 + i] = run;   // cursor
        run += c[i];
    }
    if (t == 1023) row_start[8192] = run;
    if (t == 0) {
        int zr = 0;
        for (int i = 0; i < 10; ++i) { zrs[i] = zr; zcur[i] = zr; zr += zcnt[i]; }
        zrs[10] = zr;
    }
}

__global__ void k_scatter(const int* __restrict__ eidx, const float* __restrict__ na,
                          int* __restrict__ cursor, int* __restrict__ elist,
                          int* __restrict__ zcur, int* __restrict__ znodes) {
    int e = blockIdx.x * 256 + threadIdx.x;
    if (e < NE) {
        int p = atomicAdd(&cursor[eidx[NE + e]], 1);
        elist[p] = e;
    }
    if (e < NN) {
        const float* row = na + (size_t)e * 10;
        int z = 0;
        #pragma unroll
        for (int w = 1; w < 10; ++w) if (row[w] > 0.5f) z = w;
        int p = atomicAdd(&zcur[z], 1);
        znodes[p] = e;
    }
}

// ---------------- weight prep: transposes + W4^T split-bf16 frag planes ----------------
__global__ __launch_bounds__(256) void k_prep(const float* __restrict__ W1, const float* __restrict__ W2,
                                              const float* __restrict__ W3, const float* __restrict__ W4,
                                              float* __restrict__ W1T, float* __restrict__ W2T,
                                              float* __restrict__ W3T, u16* __restrict__ W4Th,
                                              u16* __restrict__ W4Tl) {
    int t = blockIdx.x * 256 + threadIdx.x;
    if (t < 512) { int c = t >> 3, k = t & 7; W1T[t] = W1[k * 64 + c]; }
    if (t < 4096) {
        int c = t >> 6, k = t & 63;
        W2T[t] = W2[k * 64 + c];
        W3T[t] = W3[k * 64 + c];
    }
    if (t < 32768) {
        int c = t >> 6, k = t & 63;
        float v = W4[k * 512 + c];
        unsigned h = bf16_rne(v);
        float fh = __uint_as_float(h << 16);
        unsigned lo = bf16_rne(v - fh);
        W4Th[t] = (u16)h;
        W4Tl[t] = (u16)lo;
    }
}

// ---------------- x = node_feats @ W_up / sqrt(128) ----------------
__global__ __launch_bounds__(256) void k_x(const float* __restrict__ nf,
                                           const float* __restrict__ Wup,
                                           float* __restrict__ x) {
    __shared__ float nf_s[16][128];
    int n0 = blockIdx.x * 16;
    int t = threadIdx.x;
    for (int i = t; i < 16 * 128; i += 256) nf_s[i >> 7][i & 127] = nf[n0 * 128 + i];
    __syncthreads();
    int mc = t & 127, half = t >> 7;
    float acc[8];
    #pragma unroll
    for (int j = 0; j < 8; ++j) acc[j] = 0.f;
    for (int k = 0; k < 128; ++k) {
        float w = Wup[k * 128 + mc];
        #pragma unroll
        for (int j = 0; j < 8; ++j) acc[j] += nf_s[half * 8 + j][k] * w;
    }
    const float rs = 0.08838834764831845f;  // 1/sqrt(128)
    #pragma unroll
    for (int j = 0; j < 8; ++j) x[(n0 + half * 8 + j) * 128 + mc] = acc[j] * rs;
}

// ---------------- C precompute -> split-bf16 in MFMA A-frag layout ----------------
__global__ __launch_bounds__(256) void k_C(const float* __restrict__ Wlin,
                                           const float* __restrict__ Wskip,
                                           u16* __restrict__ CH, u16* __restrict__ CL) {
    __shared__ float wl_s[16][128];
    int b = blockIdx.x;
    int lz = b >> 3, ut = b & 7;
    int l = lz / 10, z = lz % 10;
    int t = threadIdx.x;
    for (int i = t; i < 16 * 128; i += 256) {
        int u = i >> 7, v = i & 127;
        wl_s[u][v] = Wlin[(l * 128 + ut * 16 + u) * 128 + v];
    }
    __syncthreads();
    int u2 = t & 127, uh = t >> 7;
    float acc[8];
    #pragma unroll
    for (int r = 0; r < 8; ++r) acc[r] = 0.f;
    const float* Wsk = Wskip + ((size_t)l * 128 * 10 + z) * 128 + u2;  // stride over v: 1280
    for (int v = 0; v < 128; v += 4) {
        float s0 = Wsk[(size_t)(v + 0) * 1280];
        float s1 = Wsk[(size_t)(v + 1) * 1280];
        float s2 = Wsk[(size_t)(v + 2) * 1280];
        float s3 = Wsk[(size_t)(v + 3) * 1280];
        #pragma unroll
        for (int r = 0; r < 8; ++r) {
            int u = uh * 8 + r;
            acc[r] += wl_s[u][v] * s0 + wl_s[u][v + 1] * s1
                    + wl_s[u][v + 2] * s2 + wl_s[u][v + 3] * s3;
        }
    }
    const float scale = 3.0881618e-04f;  // (1/sqrt(128)/8) * (1/sqrt(1280))
    int kc = ut * 2 + uh;
    u16x8 vh, vl;
    #pragma unroll
    for (int r = 0; r < 8; ++r) {
        float v = acc[r] * scale;
        unsigned h = bf16_rne(v);
        float fh = __uint_as_float(h << 16);
        unsigned lo = bf16_rne(v - fh);
        vh[r] = (u16)h;
        vl[r] = (u16)lo;
    }
    size_t off = ((size_t)(lz * 16 + kc) * 128 + u2) * 8;
    *(u16x8*)(CH + off) = vh;
    *(u16x8*)(CL + off) = vl;
}

// ---------------- edge MLP (VALU, weights-in-VGPR) + W4 GEMM (split-bf16 MFMA) -> A ----------------
// 32 edges/block, 256 threads. LDS ~26 KB.
__global__ __launch_bounds__(256) void k_edge(const float* __restrict__ ef,
                                              const int* __restrict__ eidx,
                                              const float* __restrict__ b1, const float* __restrict__ b2,
                                              const float* __restrict__ b3, const float* __restrict__ b4,
                                              const float* __restrict__ W1T, const float* __restrict__ W2T,
                                              const float* __restrict__ W3T,
                                              const u16* __restrict__ W4Th, const u16* __restrict__ W4Tl,
                                              const float* __restrict__ x,
                                              float* __restrict__ A) {
    __shared__ float ef_s[32][8];
    __shared__ float ha[32][64];
    __shared__ float hb[32][64];
    __shared__ u16 HFh[32 * 72];   // H split-bf16, row stride 72 (bank-spread)
    __shared__ u16 HFl[32 * 72];
    __shared__ int srcs[32];
    int t = threadIdx.x;
    int e0 = blockIdx.x * 32;
    ef_s[t >> 3][t & 7] = ef[e0 * 8 + t];
    if (t < 32) srcs[t] = eidx[e0 + t];
    __syncthreads();
    int col = t & 63, wv = t >> 6;
    // ---- layer1: 8 -> 64 ----
    {
        float4 w1a = *(const float4*)(W1T + col * 8);
        float4 w1b = *(const float4*)(W1T + col * 8 + 4);
        float bb = b1[col];
        #pragma unroll
        for (int r = 0; r < 8; ++r) {
            int e = wv * 8 + r;
            const float4* efp = (const float4*)ef_s[e];
            float4 f0 = efp[0], f1 = efp[1];
            float s = bb + f0.x * w1a.x + f0.y * w1a.y + f0.z * w1a.z + f0.w * w1a.w
                        + f1.x * w1b.x + f1.y * w1b.y + f1.z * w1b.z + f1.w * w1b.w;
            ha[e][col] = s / (1.f + expf(-s));
        }
    }
    __syncthreads();
    // ---- layer2: 64 -> 64 (weight column in VGPRs, activations via LDS broadcast) ----
    {
        const float4* wp = (const float4*)(W2T + col * 64);
        float4 wc[16];
        #pragma unroll
        for (int i = 0; i < 16; ++i) wc[i] = wp[i];
        float bb = b2[col];
        #pragma unroll
        for (int r = 0; r < 8; ++r) {
            int e = wv * 8 + r;
            const float4* hp = (const float4*)ha[e];
            float s = bb;
            #pragma unroll
            for (int i = 0; i < 16; ++i) {
                float4 h4 = hp[i];
                s += h4.x * wc[i].x + h4.y * wc[i].y + h4.z * wc[i].z + h4.w * wc[i].w;
            }
            hb[e][col] = s / (1.f + expf(-s));
        }
    }
    __syncthreads();
    // ---- layer3: 64 -> 64 ----
    {
        const float4* wp = (const float4*)(W3T + col * 64);
        float4 wc[16];
        #pragma unroll
        for (int i = 0; i < 16; ++i) wc[i] = wp[i];
        float bb = b3[col];
        #pragma unroll
        for (int r = 0; r < 8; ++r) {
            int e = wv * 8 + r;
            const float4* hp = (const float4*)hb[e];
            float s = bb;
            #pragma unroll
            for (int i = 0; i < 16; ++i) {
                float4 h4 = hp[i];
                s += h4.x * wc[i].x + h4.y * wc[i].y + h4.z * wc[i].z + h4.w * wc[i].w;
            }
            ha[e][col] = s / (1.f + expf(-s));
        }
    }
    __syncthreads();
    // ---- split H -> bf16 hi/lo fragment buffers ----
    {
        int i0 = t * 8;
        int e = i0 >> 6, k = i0 & 63;
        const float* hp = &ha[e][k];
        u16x8 vh, vl;
        #pragma unroll
        for (int r = 0; r < 8; ++r) {
            float v = hp[r];
            unsigned h = bf16_rne(v);
            float fh = __uint_as_float(h << 16);
            unsigned lo = bf16_rne(v - fh);
            vh[r] = (u16)h;
            vl[r] = (u16)lo;
        }
        *(u16x8*)&HFh[e * 72 + k] = vh;
        *(u16x8*)&HFl[e * 72 + k] = vl;
    }
    __syncthreads();
    // ---- GEMM: tpw[32e][512] = H[32e][64k] @ W4, split-bf16 MFMA; fused bias + x epilogue ----
    int lane = t & 63;
    int eloc = lane & 15, kq = lane >> 4;
    int ntile = wv & 1, mhalf = wv >> 1;
    int e = ntile * 16 + eloc;
    const u16* hfh = &HFh[e * 72 + kq * 8];
    const u16* hfl = &HFl[e * 72 + kq * 8];
    bf16x8 bH0 = *(const bf16x8*)hfh;
    bf16x8 bH1 = *(const bf16x8*)(hfh + 32);
    bf16x8 bL0 = *(const bf16x8*)hfl;
    bf16x8 bL1 = *(const bf16x8*)(hfl + 32);
    const float* xrow = x + (size_t)srcs[e] * 128;
    float* arow = A + (size_t)(e0 + e) * 512;
    #pragma unroll 2
    for (int mt = 0; mt < 16; ++mt) {
        int m0 = mhalf * 256 + mt * 16;
        const u16* ap = W4Th + (m0 + eloc) * 64 + kq * 8;
        const u16* apl = W4Tl + (m0 + eloc) * 64 + kq * 8;
        bf16x8 aH0 = *(const bf16x8*)ap;
        bf16x8 aH1 = *(const bf16x8*)(ap + 32);
        bf16x8 aL0 = *(const bf16x8*)apl;
        bf16x8 aL1 = *(const bf16x8*)(apl + 32);
        f32x4 acc = (f32x4){0.f, 0.f, 0.f, 0.f};
        acc = __builtin_amdgcn_mfma_f32_16x16x32_bf16(aH0, bH0, acc, 0, 0, 0);
        acc = __builtin_amdgcn_mfma_f32_16x16x32_bf16(aH1, bH1, acc, 0, 0, 0);
        acc = __builtin_amdgcn_mfma_f32_16x16x32_bf16(aH0, bL0, acc, 0, 0, 0);
        acc = __builtin_amdgcn_mfma_f32_16x16x32_bf16(aH1, bL1, acc, 0, 0, 0);
        acc = __builtin_amdgcn_mfma_f32_16x16x32_bf16(aL0, bH0, acc, 0, 0, 0);
        acc = __builtin_amdgcn_mfma_f32_16x16x32_bf16(aL1, bH1, acc, 0, 0, 0);
        int c0 = m0 + kq * 4;                 // D row = kq*4 + reg (verified mapping)
        float4 b4v = *(const float4*)(b4 + c0);
        float4 xv = *(const float4*)(xrow + (c0 & 127));
        float4 o;
        o.x = (acc[0] + b4v.x) * xv.x;
        o.y = (acc[1] + b4v.y) * xv.y;
        o.z = (acc[2] + b4v.z) * xv.z;
        o.w = (acc[3] + b4v.w) * xv.w;
        *(float4*)(arow + c0) = o;
    }
}

// ---------------- per-node msg accumulation -> split-bf16 planes [m][n][u] ----------------
__global__ __launch_bounds__(256) void k_msgs(const float* __restrict__ A,
                                              const float* __restrict__ Y,
                                              const int* __restrict__ row_start,
                                              const int* __restrict__ elist,
                                              u16* __restrict__ MH, u16* __restrict__ ML) {
    __shared__ int el_s[CAP];
    int n = blockIdx.x;
    int t = threadIdx.x;
    int r0 = row_start[n], r1 = row_start[n + 1];
    int k = r1 - r0;
    for (int i = t; i < k && i < CAP; i += 256) el_s[i] = elist[r0 + i];
    __syncthreads();
    if (t == 0 && k <= CAP) {  // canonical order -> deterministic f32 sums
        for (int i = 1; i < k; ++i) {
            int key = el_s[i];
            int j = i - 1;
            while (j >= 0 && el_s[j] > key) { el_s[j + 1] = el_s[j]; --j; }
            el_s[j + 1] = key;
        }
    }
    __syncthreads();
    int mc = t & 127, hi = t >> 7;
    float acc[8];
    #pragma unroll
    for (int q = 0; q < 8; ++q) acc[q] = 0.f;
    for (int j = 0; j < k; ++j) {
        int e = (j < CAP) ? el_s[j] : elist[r0 + j];
        const float* Ae = A + (size_t)e * 512;
        const float* Ye = Y + e * 16 + hi * 8;
        float y[8];
        #pragma unroll
        for (int q = 0; q < 8; ++q) y[q] = Ye[q];
        if (hi == 0) {
            float a0 = Ae[mc], a1 = Ae[128 + mc], a2 = Ae[256 + mc];
            acc[0] += a0 * y[0];
            acc[1] += a1 * y[1]; acc[2] += a1 * y[2]; acc[3] += a1 * y[3];
            acc[4] += a2 * y[4]; acc[5] += a2 * y[5]; acc[6] += a2 * y[6]; acc[7] += a2 * y[7];
        } else {
            float a2 = Ae[256 + mc], a3 = Ae[384 + mc];
            acc[0] += a2 * y[0];
            #pragma unroll
            for (int q = 1; q < 8; ++q) acc[q] += a3 * y[q];
        }
    }
    #pragma unroll
    for (int q = 0; q < 8; ++q) {
        int m = hi * 8 + q;
        float v = acc[q];
        unsigned h = bf16_rne(v);
        float fh = __uint_as_float(h << 16);
        unsigned lo = bf16_rne(v - fh);
        size_t off = ((size_t)m * 8192 + n) * 128 + mc;
        MH[off] = (u16)h;
        ML[off] = (u16)lo;
    }
}

// ---------------- z-grouped split-bf16 MFMA contraction ----------------
__global__ __launch_bounds__(256) void k_contract(const u16* __restrict__ MH,
                                                  const u16* __restrict__ ML,
                                                  const u16* __restrict__ CH,
                                                  const u16* __restrict__ CL,
                                                  const int* __restrict__ zrs,
                                                  const int* __restrict__ znodes,
                                                  float* __restrict__ Dtmp) {
    int bx = blockIdx.x;
    int z = bx / (16 * NTMAX);
    int rem = bx % (16 * NTMAX);
    int plane = rem / NTMAX;
    int tile = rem % NTMAX;
    int l = (plane >= 9) ? 3 : (plane >= 4) ? 2 : (plane >= 1) ? 1 : 0;
    int base = zrs[z];
    int cz = zrs[z + 1] - base;
    int p0 = tile * 64;
    if (p0 >= cz) return;
    __shared__ int nid_s[64];
    int t = threadIdx.x;
    if (t < 64) nid_s[t] = (p0 + t < cz) ? znodes[base + p0 + t] : -1;
    __syncthreads();
    int w = t >> 6;
    int lane = t & 63;
    int colq = lane & 15;
    int krow = lane >> 4;
    int lz = l * 10 + z;
    f32x4 acc[2][4];
    #pragma unroll
    for (int i = 0; i < 2; ++i)
        #pragma unroll
        for (int j = 0; j < 4; ++j) acc[i][j] = (f32x4){0.f, 0.f, 0.f, 0.f};
    int nids[4];
    #pragma unroll
    for (int nt = 0; nt < 4; ++nt) {
        int v = nid_s[nt * 16 + colq];
        nids[nt] = (v < 0) ? 0 : v;
    }
    const u16* MHm = MH + (size_t)plane * (8192 * 128);
    const u16* MLm = ML + (size_t)plane * (8192 * 128);
    int u0 = w * 32 + colq;
    #pragma unroll
    for (int kt = 0; kt < 4; ++kt) {
        int kc = kt * 4 + krow;
        size_t abase = (size_t)(lz * 16 + kc) * 128;
        bf16x8 aH0 = *(const bf16x8*)(CH + (abase + u0) * 8);
        bf16x8 aL0 = *(const bf16x8*)(CL + (abase + u0) * 8);
        bf16x8 aH1 = *(const bf16x8*)(CH + (abase + u0 + 16) * 8);
        bf16x8 aL1 = *(const bf16x8*)(CL + (abase + u0 + 16) * 8);
        #pragma unroll
        for (int nt = 0; nt < 4; ++nt) {
            size_t boff = ((size_t)nids[nt] * 16 + kc) * 8;
            bf16x8 bH = *(const bf16x8*)(MHm + boff);
            bf16x8 bL = *(const bf16x8*)(MLm + boff);
            acc[0][nt] = __builtin_amdgcn_mfma_f32_16x16x32_bf16(aH0, bH, acc[0][nt], 0, 0, 0);
            acc[0][nt] = __builtin_amdgcn_mfma_f32_16x16x32_bf16(aH0, bL, acc[0][nt], 0, 0, 0);
            acc[0][nt] = __builtin_amdgcn_mfma_f32_16x16x32_bf16(aL0, bH, acc[0][nt], 0, 0, 0);
            acc[1][nt] = __builtin_amdgcn_mfma_f32_16x16x32_bf16(aH1, bH, acc[1][nt], 0, 0, 0);
            acc[1][nt] = __builtin_amdgcn_mfma_f32_16x16x32_bf16(aH1, bL, acc[1][nt], 0, 0, 0);
            acc[1][nt] = __builtin_amdgcn_mfma_f32_16x16x32_bf16(aL1, bH, acc[1][nt], 0, 0, 0);
        }
    }
    #pragma unroll
    for (int nt = 0; nt < 4; ++nt) {
        int nid = nid_s[nt * 16 + colq];
        if (nid < 0) continue;
        #pragma unroll
        for (int mt = 0; mt < 2; ++mt) {
            int up = w * 32 + mt * 16 + krow * 4;
            *(f32x4*)(Dtmp + ((size_t)plane * 8192 + nid) * 128 + up) = acc[mt][nt];
        }
    }
}

// ---------------- transpose-copy Dtmp[m][n][u] -> out[n][u][m] ----------------
__global__ __launch_bounds__(256) void k_copy(const float* __restrict__ Dtmp,
                                              float* __restrict__ out) {
    __shared__ float s[8 * 128 * 17];
    int n0 = blockIdx.x * 8;
    int t = threadIdx.x;
    for (int m = 0; m < 16; ++m) {
        #pragma unroll
        for (int it = 0; it < 4; ++it) {
            int i = it * 256 + t;  // i = nn*128 + u
            float v = Dtmp[(size_t)m * (8192 * 128) + (size_t)n0 * 128 + i];
            s[i * 17 + m] = v;
        }
    }
    __syncthreads();
    #pragma unroll
    for (int it = 0; it < 4; ++it) {
        int i = it * 256 + t;
        const float* sp = &s[i * 17];
        float4* dst = (float4*)(out + (size_t)n0 * 2048 + (size_t)i * 16);
        dst[0] = make_float4(sp[0], sp[1], sp[2], sp[3]);
        dst[1] = make_float4(sp[4], sp[5], sp[6], sp[7]);
        dst[2] = make_float4(sp[8], sp[9], sp[10], sp[11]);
        dst[3] = make_float4(sp[12], sp[13], sp[14], sp[15]);
    }
}

extern "C" void kernel_launch(void* const* d_in, const int* in_sizes, int n_in,
                              void* d_out, int out_size, void* d_ws, size_t ws_size,
                              hipStream_t stream) {
    const float* na   = (const float*)d_in[0];
    const float* nf   = (const float*)d_in[1];
    const float* ea   = (const float*)d_in[2];
    const float* ef   = (const float*)d_in[3];
    const int*   eidx = (const int*)d_in[4];
    const float* Wup  = (const float*)d_in[5];
    const float* W1   = (const float*)d_in[6];
    const float* b1   = (const float*)d_in[7];
    const float* W2   = (const float*)d_in[8];
    const float* b2   = (const float*)d_in[9];
    const float* W3   = (const float*)d_in[10];
    const float* b3   = (const float*)d_in[11];
    const float* W4   = (const float*)d_in[12];
    const float* b4   = (const float*)d_in[13];
    const float* Wlin = (const float*)d_in[14];
    const float* Wskip= (const float*)d_in[15];
    float* out = (float*)d_out;

    char* ws = (char*)d_ws;
    float* A        = (float*)(ws + WS_R1);
    float* Dtmp     = (float*)(ws + WS_R1);     // reuses A's region after k_msgs
    float* x        = (float*)(ws + WS_X);
    u16*   CH       = (u16*)(ws + WS_CH);
    u16*   CL       = (u16*)(ws + WS_CL);
    int*   counts   = (int*)(ws + WS_COUNTS);   // becomes cursor after k_scan
    int*   zcnt     = (int*)(ws + WS_ZCNT);
    int*   rowstart = (int*)(ws + WS_ROWSTART);
    int*   zrs      = (int*)(ws + WS_ZRS);
    int*   zcur     = (int*)(ws + WS_ZCUR);
    int*   elist    = (int*)(ws + WS_ELIST);
    int*   znodes   = (int*)(ws + WS_ZNODES);

    // d_out scratch: prep weights (k_prep -> k_edge), then MH/ML (k_msgs -> k_contract)
    float* W1T  = (float*)d_out;
    float* W2T  = W1T + 512;
    float* W3T  = W1T + 4608;
    u16*   W4Th = (u16*)((char*)d_out + 34816);
    u16*   W4Tl = (u16*)((char*)d_out + 100352);
    u16*   MH   = (u16*)d_out;
    u16*   ML   = MH + 16777216;

    hipMemsetAsync(counts, 0, 32768 + 64, stream);  // counts + zcnt
    k_prep<<<128, 256, 0, stream>>>(W1, W2, W3, W4, W1T, W2T, W3T, W4Th, W4Tl);
    k_count<<<NE / 256, 256, 0, stream>>>(eidx, na, counts, zcnt);
    k_scan<<<1, 1024, 0, stream>>>(counts, rowstart, zcnt, zrs, zcur);
    k_scatter<<<NE / 256, 256, 0, stream>>>(eidx, na, counts, elist, zcur, znodes);
    k_x<<<NN / 16, 256, 0, stream>>>(nf, Wup, x);
    k_C<<<320, 256, 0, stream>>>(Wlin, Wskip, CH, CL);
    k_edge<<<NE / 32, 256, 0, stream>>>(ef, eidx, b1, b2, b3, b4,
                                        W1T, W2T, W3T, W4Th, W4Tl, x, A);
    k_msgs<<<NN, 256, 0, stream>>>(A, ea, rowstart, elist, MH, ML);
    k_contract<<<10 * 16 * NTMAX, 256, 0, stream>>>(MH, ML, CH, CL, zrs, znodes, Dtmp);
    k_copy<<<NN / 8, 256, 0, stream>>>(Dtmp, out);
}